// Round 1
// baseline (5293.403 us; speedup 1.0000x reference)
//
#include <hip/hip_runtime.h>
#include <math.h>

#define B 8
#define C 64
#define L 2048
#define CS 256
#define BCL  (B*C*L)    // 1048576
#define BCSL (B*CS*L)   // 4194304

__device__ __forceinline__ float gelu(float x) {
    return 0.5f * x * (1.0f + erff(x * 0.70710678118654752440f));
}

struct Combo { const float* p[6]; float c[6]; int n; };

// -------------------- conv (k=3, pad 1) --------------------
// grid: (L/64, B, OCtot/64), block 256. Each block: 64 out-ch x 64 positions.
// Thread: 4 out-ch x 4 positions. K blocked by 32 input channels via LDS.
template<int IC, int ACT>  // ACT: 0 none, 1 gelu, 2 film+gelu
__global__ __launch_bounds__(256) void conv_k(Combo in, const float* __restrict__ w,
        const float* __restrict__ bias, const float* __restrict__ cond,
        float* __restrict__ out, int OCtot) {
    __shared__ float xs[32][66];
    __shared__ float wl[32][3][64];
    const int tid = threadIdx.x;
    const int l0  = blockIdx.x * 64;
    const int b   = blockIdx.y;
    const int oc0 = blockIdx.z * 64;
    const int o0  = (tid & 15) * 4;
    const int lq  = (tid >> 4) * 4;
    float acc[4][4] = {};
    for (int icb = 0; icb < IC/32; ++icb) {
        const int ic0 = icb * 32;
        for (int idx = tid; idx < 32*3*64; idx += 256) {
            int o = idx & 63, t = idx >> 6, k = t % 3, i = t / 3;
            wl[i][k][o] = w[(size_t)(oc0 + o) * (IC*3) + (size_t)(ic0 + i) * 3 + k];
        }
        for (int idx = tid; idx < 32*66; idx += 256) {
            int i = idx / 66, p = idx % 66;
            int gl = l0 - 1 + p;
            float v = 0.0f;
            if (gl >= 0 && gl < L) {
                size_t base = ((size_t)b * IC + ic0 + i) * L + gl;
                v = in.p[0][base];
                #pragma unroll
                for (int t = 1; t < 6; ++t)
                    if (t < in.n) v += in.c[t] * in.p[t][base];
            }
            xs[i][p] = v;
        }
        __syncthreads();
        #pragma unroll 4
        for (int i = 0; i < 32; ++i) {
            float x0 = xs[i][lq+0], x1 = xs[i][lq+1], x2 = xs[i][lq+2],
                  x3 = xs[i][lq+3], x4 = xs[i][lq+4], x5 = xs[i][lq+5];
            #pragma unroll
            for (int oo = 0; oo < 4; ++oo) {
                float a0 = wl[i][0][o0+oo], a1 = wl[i][1][o0+oo], a2 = wl[i][2][o0+oo];
                acc[oo][0] += a0*x0 + a1*x1 + a2*x2;
                acc[oo][1] += a0*x1 + a1*x2 + a2*x3;
                acc[oo][2] += a0*x2 + a1*x3 + a2*x4;
                acc[oo][3] += a0*x3 + a1*x4 + a2*x5;
            }
        }
        __syncthreads();
    }
    #pragma unroll
    for (int oo = 0; oo < 4; ++oo) {
        int o = oc0 + o0 + oo;
        float bv = bias[o];
        float g = 0.f, be = 0.f;
        if (ACT == 2) { g = cond[o0+oo]; be = cond[64 + o0 + oo]; }
        float4 r;
        float* rp = &r.x;
        #pragma unroll
        for (int dl = 0; dl < 4; ++dl) {
            float v = acc[oo][dl] + bv;
            if (ACT == 2) v = (1.0f + g) * v + be;
            if (ACT >= 1) v = gelu(v);
            rp[dl] = v;
        }
        *(float4*)&out[((size_t)b * OCtot + o) * L + l0 + lq] = r;
    }
}

// -------------------- cond MLP (t -> gamma/beta) --------------------
__global__ void cond_k(float t, const float* __restrict__ tw1, const float* __restrict__ tb1,
                       const float* __restrict__ tw2, const float* __restrict__ tb2,
                       const float* __restrict__ cw, const float* __restrict__ cb,
                       float* __restrict__ cond) {
    __shared__ float te1[16], te2[16];
    int tid = threadIdx.x;
    if (tid < 16) te1[tid] = gelu(t * tw1[tid] + tb1[tid]);
    __syncthreads();
    if (tid < 16) {
        float s = tb2[tid];
        for (int k = 0; k < 16; ++k) s += te1[k] * tw2[tid*16+k];
        te2[tid] = s;
    }
    __syncthreads();
    float s = cb[tid];
    for (int j = 0; j < 16; ++j) s += te2[j] * cw[tid*16+j];
    cond[tid] = s;
}

// -------------------- wavelet part --------------------
__global__ __launch_bounds__(256) void rowmax_k(const float* __restrict__ a, float* __restrict__ bm) {
    __shared__ float red[256];
    int row = blockIdx.x;
    const float* p = a + (size_t)row * L;
    float m = -1e30f;
    for (int t = threadIdx.x; t < L; t += 256) m = fmaxf(m, p[t]);
    red[threadIdx.x] = m;
    __syncthreads();
    for (int s = 128; s > 0; s >>= 1) {
        if (threadIdx.x < s) red[threadIdx.x] = fmaxf(red[threadIdx.x], red[threadIdx.x + s]);
        __syncthreads();
    }
    if (threadIdx.x == 0) bm[row] = red[0];
}

__global__ __launch_bounds__(256) void mlp_k(const float* __restrict__ bm,
    const float* __restrict__ sw1, const float* __restrict__ sb1,
    const float* __restrict__ sw2, const float* __restrict__ sb2,
    const float* __restrict__ sw3, const float* __restrict__ sb3,
    float* __restrict__ filt) {
    __shared__ float m[8][64], f1[8][32], f2[8][32], raw[8][16], nrm[8][2];
    int tid = threadIdx.x;
    for (int i = tid; i < 512; i += 256) m[i >> 6][i & 63] = bm[i];
    __syncthreads();
    {
        int b = tid >> 5, h = tid & 31;
        float s = sb1[h];
        for (int c = 0; c < 64; ++c) s += m[b][c] * sw1[h*64+c];
        f1[b][h] = gelu(s);
    }
    __syncthreads();
    {
        int b = tid >> 5, h = tid & 31;
        float s = sb2[h];
        for (int k = 0; k < 32; ++k) s += f1[b][k] * sw2[h*32+k];
        f2[b][h] = gelu(s);
    }
    __syncthreads();
    if (tid < 128) {
        int b = tid >> 4, j = tid & 15;
        float s = sb3[j];
        for (int k = 0; k < 32; ++k) s += f2[b][k] * sw3[j*32+k];
        raw[b][j] = s;
    }
    __syncthreads();
    if (tid < 16) {
        int b = tid >> 1, half = tid & 1;
        float s = 0.f;
        for (int j = 0; j < 8; ++j) { float v = raw[b][half*8+j]; s += v*v; }
        nrm[b][half] = sqrtf(s);
    }
    __syncthreads();
    if (tid < 16) {
        int half = tid >> 3;
        float s = 0.f;
        for (int b = 0; b < 8; ++b) s += raw[b][tid] / nrm[b][half];
        filt[tid] = s * 0.125f;
    }
}

__global__ __launch_bounds__(256) void wconv_k(const float* __restrict__ ap,
    const float* __restrict__ filt, float* __restrict__ apOut,
    float* __restrict__ stacked, int lev) {
    __shared__ float f[16];
    if (threadIdx.x < 16) f[threadIdx.x] = filt[threadIdx.x];
    __syncthreads();
    size_t idx = (size_t)blockIdx.x * 256 + threadIdx.x;  // < 1048576
    int l = (int)(idx & 2047);
    size_t bc = idx >> 11;
    int c = (int)(bc & 63), b = (int)(bc >> 6);
    const float* row = ap + (bc << 11);
    float lo = 0.f, hi = 0.f;
    #pragma unroll
    for (int k = 0; k < 8; ++k) {
        int mI = l + k - 3;
        mI = mI < 0 ? -mI : (mI >= L ? 2*L - 2 - mI : mI);
        float v = row[mI];
        lo += v * f[k];
        hi += v * f[8+k];
    }
    apOut[idx] = lo;
    stacked[((size_t)b * CS + (size_t)(lev+1) * 64 + c) * L + l] = hi;
}

__global__ __launch_bounds__(256) void copyx_k(const float* __restrict__ x, float* __restrict__ st) {
    size_t i = (size_t)blockIdx.x * 256 + threadIdx.x;  // < 1048576
    size_t b = i >> 17, rem = i & 131071;
    st[b * ((size_t)CS*L) + rem] = x[i];
}

__global__ __launch_bounds__(256) void copy4_k(const float* __restrict__ s, float* __restrict__ d) {
    size_t i = (size_t)blockIdx.x * 256 + threadIdx.x;  // float4 idx < 1048576
    ((float4*)d)[i] = ((const float4*)s)[i];
}

// -------------------- RK y update --------------------
__global__ __launch_bounds__(256) void yup_k(float* __restrict__ y,
    const float* __restrict__ a, float ca, const float* __restrict__ b_, float cb_,
    const float* __restrict__ c_, float cc_, const float* __restrict__ d_, float cd_,
    const float* __restrict__ e_, float ce_) {
    size_t i = (size_t)blockIdx.x * 256 + threadIdx.x;  // float4 idx
    float4 v = ((float4*)y)[i];
    float4 A = ((const float4*)a)[i];
    float4 Bv = ((const float4*)b_)[i];
    float4 Cv = ((const float4*)c_)[i];
    float4 Dv = ((const float4*)d_)[i];
    float4 Ev = ((const float4*)e_)[i];
    v.x += ca*A.x + cb_*Bv.x + cc_*Cv.x + cd_*Dv.x + ce_*Ev.x;
    v.y += ca*A.y + cb_*Bv.y + cc_*Cv.y + cd_*Dv.y + ce_*Ev.y;
    v.z += ca*A.z + cb_*Bv.z + cc_*Cv.z + cd_*Dv.z + ce_*Ev.z;
    v.w += ca*A.w + cb_*Bv.w + cc_*Cv.w + cd_*Dv.w + ce_*Ev.w;
    ((float4*)y)[i] = v;
}

// -------------------- ecloss --------------------
__global__ __launch_bounds__(256) void ecred_k(const float* __restrict__ st,
        const float* __restrict__ dx, double* __restrict__ inner) {
    __shared__ double red[256];
    size_t base = (size_t)blockIdx.x * 4096;
    double s = 0.0;
    for (int t = threadIdx.x; t < 4096; t += 256)
        s += (double)st[base + t] * (double)dx[base + t];
    red[threadIdx.x] = s;
    __syncthreads();
    for (int k = 128; k > 0; k >>= 1) {
        if (threadIdx.x < k) red[threadIdx.x] += red[threadIdx.x + k];
        __syncthreads();
    }
    if (threadIdx.x == 0) atomicAdd(&inner[blockIdx.x >> 7], red[0]);
}

__global__ void ecfin_k(const double* __restrict__ inner, float* __restrict__ out) {
    double s = 0.0;
    for (int b = 0; b < 8; ++b) s += inner[b] * inner[b];
    out[BCSL] = (float)(s / 8.0);
}

// -------------------- output gather --------------------
__global__ __launch_bounds__(256) void gather_k(const float* __restrict__ y, float* __restrict__ out) {
    size_t q = (size_t)blockIdx.x * 256 + threadIdx.x;  // float4 idx < 1048576
    int l4 = (int)(q & 511);
    int c  = (int)((q >> 9) & 63);
    int b  = (int)((q >> 15) & 7);
    int j  = (int)(q >> 18);
    const float4* src = (const float4*)y;
    float4* dst = (float4*)out;
    dst[q] = src[((size_t)b * CS + (size_t)j * 64 + c) * 512 + l4];
}

extern "C" void kernel_launch(void* const* d_in, const int* in_sizes, int n_in,
                              void* d_out, int out_size, void* d_ws, size_t ws_size,
                              hipStream_t stream) {
    const float* x   = (const float*)d_in[0];
    const float* sw1 = (const float*)d_in[1];
    const float* sb1 = (const float*)d_in[2];
    const float* sw2 = (const float*)d_in[3];
    const float* sb2 = (const float*)d_in[4];
    const float* sw3 = (const float*)d_in[5];
    const float* sb3 = (const float*)d_in[6];
    const float* tw1 = (const float*)d_in[7];
    const float* tb1 = (const float*)d_in[8];
    const float* tw2 = (const float*)d_in[9];
    const float* tb2 = (const float*)d_in[10];
    const float* cw  = (const float*)d_in[11];
    const float* cb  = (const float*)d_in[12];
    const float* k1  = (const float*)d_in[13];
    const float* kb1 = (const float*)d_in[14];
    const float* k2  = (const float*)d_in[15];
    const float* kb2 = (const float*)d_in[16];
    const float* k3  = (const float*)d_in[17];
    const float* kb3 = (const float*)d_in[18];
    float* out = (float*)d_out;

    float* ws = (float*)d_ws;
    float* stacked = ws;
    float* y   = stacked + BCSL;
    float* s1  = y  + BCSL;
    float* s2  = s1 + BCSL;
    float* s3  = s2 + BCSL;
    float* s4  = s3 + BCSL;
    float* s5  = s4 + BCSL;
    float* h1  = s5 + BCSL;
    float* h2  = h1 + BCL;
    float* cond = h2 + BCL;
    float* bmax = cond + 128;
    float* filt = bmax + 512;
    double* inner = (double*)(filt + 16);

    hipMemsetAsync(inner, 0, 8 * sizeof(double), stream);

    // ---- wavelet decomposition ----
    copyx_k<<<4096, 256, 0, stream>>>(x, stacked);
    const float* apIn = x;
    float* apBuf[2] = {h1, h2};
    for (int lev = 0; lev < 3; ++lev) {
        rowmax_k<<<512, 256, 0, stream>>>(apIn, bmax);
        mlp_k<<<1, 256, 0, stream>>>(bmax, sw1, sb1, sw2, sb2, sw3, sb3, filt);
        float* apOut = apBuf[lev & 1];
        wconv_k<<<4096, 256, 0, stream>>>(apIn, filt, apOut, stacked, lev);
        apIn = apOut;
    }
    copy4_k<<<4096, 256, 0, stream>>>(stacked, y);

    // ---- RK45 ----
    const float hs = 0.25f;
    auto stage = [&](float tval, const Combo& cin, float* outS) {
        cond_k<<<1, 128, 0, stream>>>(tval, tw1, tb1, tw2, tb2, cw, cb, cond);
        conv_k<256,2><<<dim3(32,8,1), 256, 0, stream>>>(cin, k1, kb1, cond, h1, 64);
        Combo c1{}; c1.p[0] = h1; c1.n = 1;
        conv_k<64,1><<<dim3(32,8,1), 256, 0, stream>>>(c1, k2, kb2, (const float*)nullptr, h2, 64);
        Combo c2{}; c2.p[0] = h2; c2.n = 1;
        conv_k<64,0><<<dim3(32,8,4), 256, 0, stream>>>(c2, k3, kb3, (const float*)nullptr, outS, 256);
    };

    for (int i = 0; i < 4; ++i) {
        float t0 = hs * (float)i;
        Combo cA{}; cA.p[0] = y; cA.n = 1;
        stage(t0, cA, s1);

        Combo cB{}; cB.p[0] = y; cB.p[1] = s1; cB.c[1] = hs*(1.f/5.f); cB.n = 2;
        stage(t0 + hs/5.f, cB, s2);

        Combo cC{}; cC.p[0] = y;
        cC.p[1] = s1; cC.c[1] = hs*(3.f/40.f);
        cC.p[2] = s2; cC.c[2] = hs*(9.f/40.f); cC.n = 3;
        stage(t0 + 3.f*hs/10.f, cC, s3);

        Combo cD{}; cD.p[0] = y;
        cD.p[1] = s1; cD.c[1] = hs*(44.f/45.f);
        cD.p[2] = s2; cD.c[2] = -hs*(56.f/15.f);
        cD.p[3] = s3; cD.c[3] = hs*(32.f/9.f); cD.n = 4;
        stage(t0 + 4.f*hs/5.f, cD, s4);

        Combo cE{}; cE.p[0] = y;
        cE.p[1] = s1; cE.c[1] = hs*(19372.f/6561.f);
        cE.p[2] = s2; cE.c[2] = -hs*(25360.f/2187.f);
        cE.p[3] = s3; cE.c[3] = hs*(64448.f/6561.f);
        cE.p[4] = s4; cE.c[4] = -hs*(212.f/729.f); cE.n = 5;
        stage(t0 + 8.f*hs/9.f, cE, s5);

        Combo cF{}; cF.p[0] = y;
        cF.p[1] = s1; cF.c[1] = hs*(9017.f/3168.f);
        cF.p[2] = s2; cF.c[2] = -hs*(355.f/33.f);
        cF.p[3] = s3; cF.c[3] = hs*(46732.f/5247.f);
        cF.p[4] = s4; cF.c[4] = hs*(49.f/176.f);
        cF.p[5] = s5; cF.c[5] = -hs*(5103.f/18656.f); cF.n = 6;
        stage(t0 + hs, cF, s2);   // s6 written into s2's buffer (b2 == 0)

        yup_k<<<4096, 256, 0, stream>>>(y,
            s1, hs*(35.f/384.f), s3, hs*(500.f/1113.f), s4, hs*(125.f/192.f),
            s5, -hs*(2187.f/6784.f), s2, hs*(11.f/84.f));
    }

    // ---- dx = ode_f(1.0, y), ecloss, outputs ----
    Combo cZ{}; cZ.p[0] = y; cZ.n = 1;
    stage(1.0f, cZ, s1);
    ecred_k<<<1024, 256, 0, stream>>>(stacked, s1, inner);
    ecfin_k<<<1, 1, 0, stream>>>(inner, out);
    gather_k<<<4096, 256, 0, stream>>>(y, out);
}